// Round 1
// baseline (384.481 us; speedup 1.0000x reference)
//
#include <hip/hip_runtime.h>

typedef __bf16 v8bf __attribute__((ext_vector_type(8)));
typedef float  v4f  __attribute__((ext_vector_type(4)));

#define D_     256
#define NH_    8
#define NL_    4
#define NP2_   4
#define HD_    32
#define BB_    4
#define LQ_    1024
#define LEN_IN_ 21760
#define BQ_    4096   // BB_*LQ_
#define DFF_   1024

// ---------------------------------------------------------------------------
// Generic bf16-MFMA GEMM:  C[M][ldc] = A[M][lda] @ Bt[N][K]^T + bias
// A is fp32 (converted on stage) or bf16; Bt is pre-transposed bf16 [N][K].
// Tile 128x128, BK=64, 4 waves (each 64x64), 16x16x32 MFMA.
// All problem dims here are exact multiples of the tile dims.
// ---------------------------------------------------------------------------
template<bool A_BF16, bool RELU, bool OUT_BF16>
__global__ __launch_bounds__(256) void gemm_tn(
    const void* __restrict__ Av, const __bf16* __restrict__ Bt,
    const float* __restrict__ bias, void* __restrict__ Cv,
    int M, int N, int K, int lda, int ldc)
{
    __shared__ alignas(16) __bf16 As[128][72];   // +8 pad: 144B row stride
    __shared__ alignas(16) __bf16 Bs[128][72];

    const int tid  = threadIdx.x;
    const int row0 = blockIdx.y * 128;
    const int col0 = blockIdx.x * 128;
    const int lane = tid & 63;
    const int wid  = tid >> 6;
    const int wm   = (wid >> 1) * 64;
    const int wn   = (wid & 1) * 64;
    const int lr   = lane & 15;
    const int lk   = lane >> 4;    // 0..3

    v4f acc[4][4];
    #pragma unroll
    for (int i = 0; i < 4; ++i)
        #pragma unroll
        for (int j = 0; j < 4; ++j) {
            acc[i][j][0] = 0.f; acc[i][j][1] = 0.f;
            acc[i][j][2] = 0.f; acc[i][j][3] = 0.f;
        }

    const int nkt = K >> 6;
    for (int kt = 0; kt < nkt; ++kt) {
        const int k0 = kt << 6;
        __syncthreads();
        #pragma unroll
        for (int i = 0; i < 4; ++i) {
            const int c  = tid + i * 256;     // chunk id, 1024 chunks of 8 elems
            const int r  = c >> 3;            // row in tile
            const int cc = c & 7;             // 8-elem chunk within row
            // --- stage A ---
            if constexpr (A_BF16) {
                const __bf16* A = (const __bf16*)Av;
                const uint4 u = *(const uint4*)(A + (size_t)(row0 + r) * lda + k0 + cc * 8);
                *(uint4*)(&As[r][cc * 8]) = u;
            } else {
                const float* A = (const float*)Av;
                const float* p = A + (size_t)(row0 + r) * lda + k0 + cc * 8;
                const float4 f0 = *(const float4*)p;
                const float4 f1 = *(const float4*)(p + 4);
                v8bf t;
                t[0] = (__bf16)f0.x; t[1] = (__bf16)f0.y;
                t[2] = (__bf16)f0.z; t[3] = (__bf16)f0.w;
                t[4] = (__bf16)f1.x; t[5] = (__bf16)f1.y;
                t[6] = (__bf16)f1.z; t[7] = (__bf16)f1.w;
                *(v8bf*)(&As[r][cc * 8]) = t;
            }
            // --- stage B (already bf16, [N][K]) ---
            const uint4 ub = *(const uint4*)(Bt + (size_t)(col0 + r) * K + k0 + cc * 8);
            *(uint4*)(&Bs[r][cc * 8]) = ub;
        }
        __syncthreads();
        #pragma unroll
        for (int kk = 0; kk < 2; ++kk) {
            v8bf a[4], b[4];
            #pragma unroll
            for (int i = 0; i < 4; ++i)
                a[i] = *(const v8bf*)(&As[wm + i * 16 + lr][kk * 32 + lk * 8]);
            #pragma unroll
            for (int j = 0; j < 4; ++j)
                b[j] = *(const v8bf*)(&Bs[wn + j * 16 + lr][kk * 32 + lk * 8]);
            #pragma unroll
            for (int i = 0; i < 4; ++i)
                #pragma unroll
                for (int j = 0; j < 4; ++j)
                    acc[i][j] = __builtin_amdgcn_mfma_f32_16x16x32_bf16(a[i], b[j], acc[i][j], 0, 0, 0);
        }
    }

    // epilogue: C[row][col], row = lk*4 + r within each 16x16 fragment
    float bv[4];
    #pragma unroll
    for (int j = 0; j < 4; ++j) bv[j] = bias[col0 + wn + j * 16 + lr];

    #pragma unroll
    for (int i = 0; i < 4; ++i) {
        #pragma unroll
        for (int j = 0; j < 4; ++j) {
            const int col = col0 + wn + j * 16 + lr;
            #pragma unroll
            for (int r = 0; r < 4; ++r) {
                const int row = row0 + wm + i * 16 + lk * 4 + r;
                float v = acc[i][j][r] + bv[j];
                if constexpr (RELU) v = fmaxf(v, 0.f);
                if constexpr (OUT_BF16)
                    ((__bf16*)Cv)[(size_t)row * ldc + col] = (__bf16)v;
                else
                    ((float*)Cv)[(size_t)row * ldc + col] = v;
            }
        }
    }
}

// ---------------------------------------------------------------------------
// small helpers
// ---------------------------------------------------------------------------
__global__ void transpose_cvt(const float* __restrict__ in, __bf16* __restrict__ out,
                              int K, int N)  // in[K][N] -> out[N][K]
{
    const int idx = blockIdx.x * 256 + threadIdx.x;
    if (idx >= K * N) return;
    const int n = idx / K;
    const int k = idx - n * K;
    out[idx] = (__bf16)in[(size_t)k * N + n];
}

__global__ void bias_cat(const float* __restrict__ a, const float* __restrict__ b,
                         float* __restrict__ out)
{
    const int i = threadIdx.x;           // 384 threads
    out[i] = (i < 256) ? a[i] : b[i - 256];
}

__global__ void add4(const float* __restrict__ a, const float* __restrict__ b,
                     float* __restrict__ o)
{
    const int i = blockIdx.x * 256 + threadIdx.x;   // over n/4 float4s
    const float4 x = ((const float4*)a)[i];
    const float4 y = ((const float4*)b)[i];
    float4 r; r.x = x.x + y.x; r.y = x.y + y.y; r.z = x.z + y.z; r.w = x.w + y.w;
    ((float4*)o)[i] = r;
}

// per (b*LQ, head): softmax over 16 attn logits + pixel-space sample coords
__global__ __launch_bounds__(256) void samp_prep(
    const float* __restrict__ offaw,   // [BQ][384]: 256 off | 128 aw
    const float* __restrict__ refp,    // [B][LQ][NL][2]
    float* __restrict__ samp)          // [BQ*NH][16][3] = {x, y, w}
{
    const int t  = blockIdx.x * 256 + threadIdx.x;   // 32768
    const int bq = t >> 3;
    const int h  = t & 7;
    const float* base = offaw + (size_t)bq * 384;
    const float* awp  = base + 256 + h * 16;

    float e[16];
    float m = -1e30f;
    #pragma unroll
    for (int j = 0; j < 16; ++j) m = fmaxf(m, awp[j]);
    float s = 0.f;
    #pragma unroll
    for (int j = 0; j < 16; ++j) { e[j] = __expf(awp[j] - m); s += e[j]; }
    const float inv = 1.f / s;

    const float SZ[4] = {128.f, 64.f, 32.f, 16.f};
    float* sp = samp + (size_t)t * 48;
    #pragma unroll
    for (int l = 0; l < 4; ++l) {
        const float rx = refp[(size_t)bq * 8 + l * 2 + 0];
        const float ry = refp[(size_t)bq * 8 + l * 2 + 1];
        const float W = SZ[l], H = SZ[l];
        #pragma unroll
        for (int p = 0; p < 4; ++p) {
            const float ox = base[h * 32 + l * 8 + p * 2 + 0];
            const float oy = base[h * 32 + l * 8 + p * 2 + 1];
            const float locx = rx + ox * (1.f / W);
            const float locy = ry + oy * (1.f / H);
            sp[(l * 4 + p) * 3 + 0] = locx * W - 0.5f;
            sp[(l * 4 + p) * 3 + 1] = locy * H - 0.5f;
            sp[(l * 4 + p) * 3 + 2] = e[l * 4 + p] * inv;
        }
    }
}

// 32-lane group per (b, q, head); lane = channel within head
__global__ __launch_bounds__(256) void ms_sample(
    const __bf16* __restrict__ val,    // [B][LEN_IN][256] bf16
    const float* __restrict__ samp,    // [BQ*NH][16][3]
    float* __restrict__ out)           // [BQ][256]
{
    const int g    = blockIdx.x * 8 + (threadIdx.x >> 5);
    const int lane = threadIdx.x & 31;
    const int bq   = g >> 3;
    const int h    = g & 7;
    const int b    = bq >> 10;

    const int   Wi[4] = {128, 64, 32, 16};
    const int   st[4] = {0, 16384, 20480, 21504};
    const float* sp = samp + (size_t)g * 48;
    const __bf16* vb = val + (size_t)b * LEN_IN_ * 256 + h * 32 + lane;

    float acc = 0.f;
    #pragma unroll
    for (int l = 0; l < 4; ++l) {
        const int W = Wi[l], H = Wi[l];
        const __bf16* vl = vb + (size_t)st[l] * 256;
        #pragma unroll
        for (int p = 0; p < 4; ++p) {
            const float x  = sp[(l * 4 + p) * 3 + 0];
            const float y  = sp[(l * 4 + p) * 3 + 1];
            const float aw = sp[(l * 4 + p) * 3 + 2];
            const float xf = floorf(x), yf = floorf(y);
            const float fx = x - xf, fy = y - yf;
            const int x0 = (int)xf, y0 = (int)yf;
            const float w00 = (1.f - fx) * (1.f - fy) * aw;
            const float w10 = fx * (1.f - fy) * aw;
            const float w01 = (1.f - fx) * fy * aw;
            const float w11 = fx * fy * aw;
            const bool xi0 = (x0 >= 0) & (x0 < W);
            const bool xi1 = (x0 + 1 >= 0) & (x0 + 1 < W);
            const bool yi0 = (y0 >= 0) & (y0 < H);
            const bool yi1 = (y0 + 1 >= 0) & (y0 + 1 < H);
            if (xi0 & yi0) acc += w00 * (float)vl[(size_t)(y0 * W + x0) * 256];
            if (xi1 & yi0) acc += w10 * (float)vl[(size_t)(y0 * W + x0 + 1) * 256];
            if (xi0 & yi1) acc += w01 * (float)vl[(size_t)((y0 + 1) * W + x0) * 256];
            if (xi1 & yi1) acc += w11 * (float)vl[(size_t)((y0 + 1) * W + x0 + 1) * 256];
        }
    }
    out[(size_t)bq * 256 + h * 32 + lane] = acc;
}

// out = LayerNorm(a + d) * g + be ; one wave per 256-wide row
__global__ __launch_bounds__(256) void ln_residual(
    const float* __restrict__ a, const float* __restrict__ d,
    const float* __restrict__ g, const float* __restrict__ be,
    float* __restrict__ out)
{
    const int row  = blockIdx.x * 4 + (threadIdx.x >> 6);
    const int lane = threadIdx.x & 63;
    const size_t base = (size_t)row * 256 + lane * 4;
    const float4 av = *(const float4*)(a + base);
    const float4 dv = *(const float4*)(d + base);
    float x0 = av.x + dv.x, x1 = av.y + dv.y, x2 = av.z + dv.z, x3 = av.w + dv.w;
    float s  = x0 + x1 + x2 + x3;
    float sq = x0 * x0 + x1 * x1 + x2 * x2 + x3 * x3;
    #pragma unroll
    for (int m = 1; m < 64; m <<= 1) {
        s  += __shfl_xor(s, m);
        sq += __shfl_xor(sq, m);
    }
    const float mean = s * (1.f / 256.f);
    const float var  = sq * (1.f / 256.f) - mean * mean;
    const float inv  = rsqrtf(var + 1e-5f);
    const float4 gv = *(const float4*)(g + lane * 4);
    const float4 bv = *(const float4*)(be + lane * 4);
    float4 r;
    r.x = (x0 - mean) * inv * gv.x + bv.x;
    r.y = (x1 - mean) * inv * gv.y + bv.y;
    r.z = (x2 - mean) * inv * gv.z + bv.z;
    r.w = (x3 - mean) * inv * gv.w + bv.w;
    *(float4*)(out + base) = r;
}

// ---------------------------------------------------------------------------
extern "C" void kernel_launch(void* const* d_in, const int* in_sizes, int n_in,
                              void* d_out, int out_size, void* d_ws, size_t ws_size,
                              hipStream_t stream)
{
    const float* tgt    = (const float*)d_in[0];
    const float* qpos   = (const float*)d_in[1];
    const float* refp   = (const float*)d_in[2];
    const float* src    = (const float*)d_in[3];
    // thermal branch (d_in[4], d_in[13..20], 23, 24) is dead code in the reference
    const float* off_w  = (const float*)d_in[5];
    const float* off_b  = (const float*)d_in[6];
    const float* aw_w   = (const float*)d_in[7];
    const float* aw_b   = (const float*)d_in[8];
    const float* val_w  = (const float*)d_in[9];
    const float* val_b  = (const float*)d_in[10];
    const float* out_w  = (const float*)d_in[11];
    const float* out_b  = (const float*)d_in[12];
    const float* ln_g   = (const float*)d_in[21];
    const float* ln_b   = (const float*)d_in[22];
    const float* w1     = (const float*)d_in[25];
    const float* b1     = (const float*)d_in[26];
    const float* w2     = (const float*)d_in[27];
    const float* b2     = (const float*)d_in[28];
    const float* ln2_g  = (const float*)d_in[29];
    const float* ln2_b  = (const float*)d_in[30];
    float* out = (float*)d_out;

    char* ws = (char*)d_ws;
    size_t woff = 0;
    auto alloc = [&](size_t bytes) { char* p = ws + woff; woff += (bytes + 255) & ~(size_t)255; return p; };

    __bf16* vwt     = (__bf16*)alloc(256 * 256 * 2);     // [256 N][256 K]
    __bf16* offawt  = (__bf16*)alloc(384 * 256 * 2);     // [384 N][256 K]
    __bf16* pwt     = (__bf16*)alloc(256 * 256 * 2);
    __bf16* w1t     = (__bf16*)alloc(1024 * 256 * 2);    // [1024 N][256 K]
    __bf16* w2t     = (__bf16*)alloc(256 * 1024 * 2);    // [256 N][1024 K]
    float*  biascat = (float*)alloc(384 * 4);
    float*  qbuf    = (float*)alloc((size_t)BQ_ * 256 * 4);
    __bf16* valb    = (__bf16*)alloc((size_t)BB_ * LEN_IN_ * 256 * 2);
    float*  offaw   = (float*)alloc((size_t)BQ_ * 384 * 4);
    float*  samp    = (float*)alloc((size_t)BQ_ * NH_ * 48 * 4);
    float*  sacc    = (float*)alloc((size_t)BQ_ * 256 * 4);
    float*  tproj   = (float*)alloc((size_t)BQ_ * 256 * 4);
    float*  tgtrgb  = (float*)alloc((size_t)BQ_ * 256 * 4);
    __bf16* hbuf    = (__bf16*)alloc((size_t)BQ_ * 1024 * 2);
    float*  t2      = (float*)alloc((size_t)BQ_ * 256 * 4);
    (void)ws_size; (void)in_sizes; (void)n_in; (void)out_size;

    // --- prep: weight transpose+convert, bias concat, q = tgt + qpos ---
    transpose_cvt<<<dim3(256), 256, 0, stream>>>(val_w, vwt, 256, 256);
    transpose_cvt<<<dim3(256), 256, 0, stream>>>(off_w, offawt, 256, 256);
    transpose_cvt<<<dim3(128), 256, 0, stream>>>(aw_w, offawt + 256 * 256, 256, 128);
    transpose_cvt<<<dim3(256), 256, 0, stream>>>(out_w, pwt, 256, 256);
    transpose_cvt<<<dim3(1024), 256, 0, stream>>>(w1, w1t, 256, 1024);
    transpose_cvt<<<dim3(1024), 256, 0, stream>>>(w2, w2t, 1024, 256);
    bias_cat<<<1, 384, 0, stream>>>(off_b, aw_b, biascat);
    add4<<<dim3(1024), 256, 0, stream>>>(tgt, qpos, qbuf);

    // --- value projection: [87040,256] = src @ vw + vb, out bf16 ---
    gemm_tn<false, false, true><<<dim3(2, 680), 256, 0, stream>>>(
        src, vwt, val_b, valb, BB_ * LEN_IN_, 256, 256, 256, 256);

    // --- offsets + attn logits: [4096,384] ---
    gemm_tn<false, false, false><<<dim3(3, 32), 256, 0, stream>>>(
        qbuf, offawt, biascat, offaw, BQ_, 384, 256, 256, 384);

    // --- softmax + sample coords ---
    samp_prep<<<dim3(128), 256, 0, stream>>>(offaw, refp, samp);

    // --- deformable sampling ---
    ms_sample<<<dim3(4096), 256, 0, stream>>>(valb, samp, sacc);

    // --- output projection ---
    gemm_tn<false, false, false><<<dim3(2, 32), 256, 0, stream>>>(
        sacc, pwt, out_b, tproj, BQ_, 256, 256, 256, 256);

    // --- LN1: tgt_rgb = LN(tgt + tproj) ---
    ln_residual<<<dim3(1024), 256, 0, stream>>>(tgt, tproj, ln_g, ln_b, tgtrgb);

    // --- FFN ---
    gemm_tn<false, true, true><<<dim3(8, 32), 256, 0, stream>>>(
        tgtrgb, w1t, b1, hbuf, BQ_, 1024, 256, 256, 1024);
    gemm_tn<true, false, false><<<dim3(2, 32), 256, 0, stream>>>(
        hbuf, w2t, b2, t2, BQ_, 256, 1024, 1024, 256);

    // --- LN2 -> output ---
    ln_residual<<<dim3(1024), 256, 0, stream>>>(tgtrgb, t2, ln2_g, ln2_b, out);
}